// Round 7
// baseline (354.419 us; speedup 1.0000x reference)
//
#include <hip/hip_runtime.h>
#include <cstdint>

typedef unsigned short u16;
using bf16x8 = __attribute__((ext_vector_type(8))) short;   // 8 bf16 = 4 VGPR
using f32x4  = __attribute__((ext_vector_type(4))) float;   // MFMA acc

struct alignas(16) V16 { uint32_t a, b, c, d; };            // 16B chunk
struct alignas(8)  U16x4 { u16 a, b, c, d; };
struct alignas(16) F4 { float x, y, z, w; };

__device__ __forceinline__ u16 f2bf(float f) {              // RNE f32->bf16
  uint32_t u = __float_as_uint(f);
  u += 0x7fffu + ((u >> 16) & 1u);
  return (u16)(u >> 16);
}
__device__ __forceinline__ float bf2f(u16 h) {
  return __uint_as_float(((uint32_t)h) << 16);
}

// async global->LDS, 16B per lane; dest = wave-uniform base + lane*16 (linear)
#define GLOAD16(g, l) __builtin_amdgcn_global_load_lds(                         \
    (const __attribute__((address_space(1))) uint32_t*)(g),                     \
    (__attribute__((address_space(3))) uint32_t*)(l), 16, 0, 0)

// ===========================================================================
// m201-geometry conv-GEMM: BM=BN=256, BK=64 slab, 8 waves (2M x 4N),
// per-wave 128x64 output (acc[8][4] = 128 VGPR).
//   Out[b][m][n] = sum_t sum_k A[m][t*256+k] * Bact[b][n+off(t)][k]
// Intensity: per K=32 per CU, LDS reads 96KB (375cy @256B/cy) vs MFMA 320cy
// -> ~85% ceiling (vs 1.56x oversubscribed in the 64x64-per-wave layout).
// LDS = 160 KiB exactly: A ring-3 (3 x 256x64 bf16 = 96KB) + B ring-2 (64KB).
// Rows 128B, swizzle chunk^=(row&7) (verified 0-conflict), applied on global
// SOURCE + ds_read side; global_load_lds dest linear (rule #21).
// 4 phases/slab: P1 {rd B.k0(4)+A.m03.k0(4); stage B(s+1) 2; bar; lgkm; 16
// MFMA} P2 {rd A.m47.k0(4); stage B(s+1) 2; ...16 MFMA, B from regs} P3/P4
// same for k1 staging A(s+2). Slab-boundary wait = vmcnt(4) (A(s+2) newer
// than needed B(s+1)) -> counted, never 0 in steady state (T3+T4), setprio
// around MFMA (T5).
// ===========================================================================
template<int MODE>
__global__ __launch_bounds__(512, 2) void gemm201_bf16(
    const u16* __restrict__ A, const u16* __restrict__ B, u16* __restrict__ otr,
    int sA, int sB, int64_t bBatch, int trStride, int64_t trBatch, int MT,
    const u16* __restrict__ zpage)
{
  constexpr int NS = (MODE == 2) ? 36 : 12;    // BK=64 slabs: NTAPS*(256/64)
  __shared__ __align__(16) u16 lds[81920];     // 160 KiB
  u16* ldsB = lds + 49152;                     // B ring-2 after A ring-3

  const int tid = threadIdx.x;
  // XCD-aware bijective swizzle (gridDim.x % 8 == 0)
  const int q = gridDim.x >> 3;
  const int flat = (blockIdx.x & 7) * q + (blockIdx.x >> 3);
  const int per_b = MT * 16;                   // 16 n-tiles of 256
  const int b = flat / per_b, rem = flat % per_b;
  const int ntile = rem / MT, mtile = rem % MT;
  const int m0 = mtile * 256, n0 = ntile * 256;
  const u16* Bb = B + (int64_t)b * bBatch;

  const int lane = tid & 63, wave = tid >> 6;
  const int wm = wave >> 2, wn = wave & 3;     // 2M x 4N waves, 128x64 each
  const int lr = lane & 15, lc = lane >> 4;

  // staging: thread -> (row srow+j*64, 16B chunk sch); swizzle const over j
  const int srow = tid >> 3, sch = tid & 7;
  const int scs = sch ^ (srow & 7);            // pre-swizzled source chunk
  const u16* aSrc[4];
  const u16* bSrc[4];
  int bRow[4];
#pragma unroll
  for (int j = 0; j < 4; ++j) {
    aSrc[j] = A + (int64_t)(m0 + srow + j * 64) * sA + scs * 8;
    bSrc[j] = Bb + (int64_t)(n0 + srow + j * 64) * sB + scs * 8;
    bRow[j] = n0 + srow + j * 64;
  }
  const int woff = wave * 512;                 // u16; dest = base+j*4096+woff

  auto stageA = [&](int s, int j0, int j1) {
    const int tap = s >> 2, kOff = tap * 256 + ((s & 3) << 6);
    u16* dst = lds + (s % 3) * 16384;
#pragma unroll
    for (int j = j0; j < j1; ++j)
      GLOAD16(aSrc[j] + kOff, dst + j * 4096 + woff);
  };
  auto stageB = [&](int s, int j0, int j1) {
    const int tap = s >> 2, kc = (s & 3) << 6;
    int off, dh = 0, dw = 0;
    if constexpr (MODE == 2) { dh = tap / 3 - 1; dw = tap % 3 - 1; off = dh * 64 + dw; }
    else                     { off = tap - 1; }
    u16* dst = ldsB + (s & 1) * 16384;
#pragma unroll
    for (int j = j0; j < j1; ++j) {
      bool ok;
      if constexpr (MODE == 2) {
        int hh = (bRow[j] >> 6) + dh, ww = (bRow[j] & 63) + dw;
        ok = ((unsigned)hh < 64u) && ((unsigned)ww < 64u);
      } else {
        ok = ((unsigned)(bRow[j] + off) < 4096u);
      }
      const u16* src = ok ? (bSrc[j] + (int64_t)off * sB + kc) : zpage;
      GLOAD16(src, dst + j * 4096 + woff);
    }
  };

  f32x4 acc[8][4];
#pragma unroll
  for (int i = 0; i < 8; ++i)
#pragma unroll
    for (int j = 0; j < 4; ++j) acc[i][j] = f32x4{0.f, 0.f, 0.f, 0.f};

  // prologue: A(0), B(0), A(1) = 12 loads; need first 8 -> vmcnt(4)
  stageA(0, 0, 4); stageB(0, 0, 4); stageA(1, 0, 4);
  asm volatile("s_waitcnt vmcnt(4)" ::: "memory");
  __builtin_amdgcn_s_barrier();
  __builtin_amdgcn_sched_barrier(0);

  for (int s = 0; s < NS; ++s) {
    const u16* As = lds + (s % 3) * 16384;
    const u16* Bs = ldsB + (s & 1) * 16384;
    bf16x8 bfr[4], af[4];

    // ---- P1: B.k0 + A.m0-3.k0; stage B(s+1) j0-1; MFMA acc[0-3][*] ----
#pragma unroll
    for (int nf = 0; nf < 4; ++nf) {
      int row = wn * 64 + nf * 16 + lr;
      bfr[nf] = *(const bf16x8*)&Bs[row * 64 + ((lc ^ (row & 7)) * 8)];
    }
#pragma unroll
    for (int mf = 0; mf < 4; ++mf) {
      int row = wm * 128 + mf * 16 + lr;
      af[mf] = *(const bf16x8*)&As[row * 64 + ((lc ^ (row & 7)) * 8)];
    }
    if (s + 1 < NS) stageB(s + 1, 0, 2);
    __builtin_amdgcn_s_barrier();
    asm volatile("s_waitcnt lgkmcnt(0)" ::: "memory");
    __builtin_amdgcn_sched_barrier(0);
    __builtin_amdgcn_s_setprio(1);
#pragma unroll
    for (int mf = 0; mf < 4; ++mf)
#pragma unroll
      for (int nf = 0; nf < 4; ++nf)
        acc[mf][nf] = __builtin_amdgcn_mfma_f32_16x16x32_bf16(af[mf], bfr[nf], acc[mf][nf], 0, 0, 0);
    __builtin_amdgcn_s_setprio(0);
    __builtin_amdgcn_s_barrier();

    // ---- P2: A.m4-7.k0; stage B(s+1) j2-3; MFMA acc[4-7][*] (B in regs) ----
#pragma unroll
    for (int mf = 0; mf < 4; ++mf) {
      int row = wm * 128 + 64 + mf * 16 + lr;
      af[mf] = *(const bf16x8*)&As[row * 64 + ((lc ^ (row & 7)) * 8)];
    }
    if (s + 1 < NS) stageB(s + 1, 2, 4);
    __builtin_amdgcn_s_barrier();
    asm volatile("s_waitcnt lgkmcnt(0)" ::: "memory");
    __builtin_amdgcn_sched_barrier(0);
    __builtin_amdgcn_s_setprio(1);
#pragma unroll
    for (int mf = 0; mf < 4; ++mf)
#pragma unroll
      for (int nf = 0; nf < 4; ++nf)
        acc[4 + mf][nf] = __builtin_amdgcn_mfma_f32_16x16x32_bf16(af[mf], bfr[nf], acc[4 + mf][nf], 0, 0, 0);
    __builtin_amdgcn_s_setprio(0);
    __builtin_amdgcn_s_barrier();

    // ---- P3: B.k1 + A.m0-3.k1; stage A(s+2) j0-1; MFMA acc[0-3][*] ----
#pragma unroll
    for (int nf = 0; nf < 4; ++nf) {
      int row = wn * 64 + nf * 16 + lr;
      bfr[nf] = *(const bf16x8*)&Bs[row * 64 + (((4 + lc) ^ (row & 7)) * 8)];
    }
#pragma unroll
    for (int mf = 0; mf < 4; ++mf) {
      int row = wm * 128 + mf * 16 + lr;
      af[mf] = *(const bf16x8*)&As[row * 64 + (((4 + lc) ^ (row & 7)) * 8)];
    }
    if (s + 2 < NS) stageA(s + 2, 0, 2);
    __builtin_amdgcn_s_barrier();
    asm volatile("s_waitcnt lgkmcnt(0)" ::: "memory");
    __builtin_amdgcn_sched_barrier(0);
    __builtin_amdgcn_s_setprio(1);
#pragma unroll
    for (int mf = 0; mf < 4; ++mf)
#pragma unroll
      for (int nf = 0; nf < 4; ++nf)
        acc[mf][nf] = __builtin_amdgcn_mfma_f32_16x16x32_bf16(af[mf], bfr[nf], acc[mf][nf], 0, 0, 0);
    __builtin_amdgcn_s_setprio(0);
    __builtin_amdgcn_s_barrier();

    // ---- P4: A.m4-7.k1; stage A(s+2) j2-3; MFMA acc[4-7][*]; slab wait ----
#pragma unroll
    for (int mf = 0; mf < 4; ++mf) {
      int row = wm * 128 + 64 + mf * 16 + lr;
      af[mf] = *(const bf16x8*)&As[row * 64 + (((4 + lc) ^ (row & 7)) * 8)];
    }
    if (s + 2 < NS) stageA(s + 2, 2, 4);
    __builtin_amdgcn_s_barrier();
    asm volatile("s_waitcnt lgkmcnt(0)" ::: "memory");
    __builtin_amdgcn_sched_barrier(0);
    __builtin_amdgcn_s_setprio(1);
#pragma unroll
    for (int mf = 0; mf < 4; ++mf)
#pragma unroll
      for (int nf = 0; nf < 4; ++nf)
        acc[4 + mf][nf] = __builtin_amdgcn_mfma_f32_16x16x32_bf16(af[mf], bfr[nf], acc[4 + mf][nf], 0, 0, 0);
    __builtin_amdgcn_s_setprio(0);
    // boundary: need A(s+1) [staged in s-1 P3/P4] + B(s+1) [this slab P1/P2];
    // only A(s+2) (4 loads) is newer -> counted wait.
    if (s + 1 < NS) {
      if (s + 2 < NS) { asm volatile("s_waitcnt vmcnt(4)" ::: "memory"); }
      else            { asm volatile("s_waitcnt vmcnt(0)" ::: "memory"); }
    }
    __builtin_amdgcn_s_barrier();
  }

  // epilogue: C/D layout col=lane&15, row=(lane>>4)*4+reg; write transposed
#pragma unroll
  for (int mf = 0; mf < 8; ++mf)
#pragma unroll
    for (int nf = 0; nf < 4; ++nf) {
      f32x4 v = acc[mf][nf];
      int m = m0 + wm * 128 + mf * 16 + lc * 4;
      int n = n0 + wn * 64 + nf * 16 + lr;
      U16x4 pk{f2bf(v[0]), f2bf(v[1]), f2bf(v[2]), f2bf(v[3])};
      *(U16x4*)(otr + trBatch * b + (int64_t)n * trStride + m) = pk;
    }
}

// ---------------------------------------------------------------------------
// 128x128 GEMM (dense stages: scores, y, gate, res)
// ---------------------------------------------------------------------------
template<int MODE, bool WR_RM, bool WR_TR>
__global__ __launch_bounds__(256) void gemm_bf16(
    const u16* __restrict__ A, const u16* __restrict__ B,
    float* __restrict__ orm, u16* __restrict__ otr,
    int Kc, int sA, int64_t aBatch,
    int sB, int64_t bBatch,
    int rmStride, int64_t rmBatch,
    int trStride, int64_t trBatch,
    int nsplit, int kStep, int64_t splitOut,
    const u16* __restrict__ zpage)
{
  constexpr int NTAPS = (MODE == 2) ? 9 : (MODE == 1 ? 3 : 1);
  __shared__ __align__(16) u16 As[128 * 32];
  __shared__ __align__(16) u16 Bs[128 * 32];

  const int tid = threadIdx.x;
  int b = blockIdx.z, split = 0;
  if (nsplit > 1) { split = b % nsplit; b /= nsplit; }
  const int m0  = blockIdx.y * 128;
  const int n0  = blockIdx.x * 128;
  const int lane = tid & 63, wave = tid >> 6;
  const int wm = wave >> 1, wn = wave & 1;
  const int lr = lane & 15, lc = lane >> 4;

  f32x4 acc[4][4];
#pragma unroll
  for (int i = 0; i < 4; ++i)
#pragma unroll
    for (int j = 0; j < 4; ++j) acc[i][j] = f32x4{0.f, 0.f, 0.f, 0.f};

  const u16* Ab = A + (int64_t)b * aBatch + split * kStep;
  const u16* Bb = B + (int64_t)b * bBatch + split * kStep;

  const int srow = tid >> 2;
  const int sc   = tid & 3;
  const int scs  = sc ^ (srow & 3);

  for (int t = 0; t < NTAPS; ++t) {
    int dh = 0, dw = 0, off = 0;
    if constexpr (MODE == 2) { dh = t / 3 - 1; dw = t % 3 - 1; off = dh * 64 + dw; }
    if constexpr (MODE == 1) { off = t - 1; }

    for (int kc = 0; kc < Kc; kc += 32) {
      const int kA = t * Kc + kc;
#pragma unroll
      for (int it = 0; it < 2; ++it) {
        int row = srow + it * 64;
        GLOAD16(Ab + (int64_t)(m0 + row) * sA + kA + scs * 8,
                &As[wave * 512 + it * 2048]);
      }
#pragma unroll
      for (int it = 0; it < 2; ++it) {
        int row = srow + it * 64;
        int l = n0 + row;
        int gl = l + off;
        bool ok = true;
        if constexpr (MODE == 2) {
          int hh = (l >> 6) + dh, ww = (l & 63) + dw;
          ok = ((unsigned)hh < 64u) && ((unsigned)ww < 64u);
        }
        if constexpr (MODE == 1) { ok = ((unsigned)gl < 4096u); }
        const u16* src = ok ? (Bb + (int64_t)gl * sB + kc + scs * 8) : zpage;
        GLOAD16(src, &Bs[wave * 512 + it * 2048]);
      }
      __syncthreads();

      bf16x8 af[4], bfr[4];
#pragma unroll
      for (int mf = 0; mf < 4; ++mf) {
        int row = wm * 64 + mf * 16 + lr;
        int cs = lc ^ (row & 3);
        af[mf] = *(const bf16x8*)&As[row * 32 + cs * 8];
      }
#pragma unroll
      for (int nf = 0; nf < 4; ++nf) {
        int row = wn * 64 + nf * 16 + lr;
        int cs = lc ^ (row & 3);
        bfr[nf] = *(const bf16x8*)&Bs[row * 32 + cs * 8];
      }
#pragma unroll
      for (int mf = 0; mf < 4; ++mf)
#pragma unroll
        for (int nf = 0; nf < 4; ++nf)
          acc[mf][nf] = __builtin_amdgcn_mfma_f32_16x16x32_bf16(af[mf], bfr[nf], acc[mf][nf], 0, 0, 0);
      __syncthreads();
    }
  }

#pragma unroll
  for (int mf = 0; mf < 4; ++mf) {
#pragma unroll
    for (int nf = 0; nf < 4; ++nf) {
      f32x4 v = acc[mf][nf];
      int m = m0 + wm * 64 + mf * 16 + lc * 4;
      int n = n0 + wn * 64 + nf * 16 + lr;
      if constexpr (WR_RM) {
        float* p = orm + splitOut * split + rmBatch * b + (int64_t)m * rmStride + n;
#pragma unroll
        for (int r = 0; r < 4; ++r) p[(int64_t)r * rmStride] = v[r];
      }
      if constexpr (WR_TR) {
        U16x4 pk{f2bf(v[0]), f2bf(v[1]), f2bf(v[2]), f2bf(v[3])};
        *(U16x4*)(otr + trBatch * b + (int64_t)n * trStride + m) = pk;
      }
    }
  }
}

// ---------------------------------------------------------------------------
// weight converts + zero page
// ---------------------------------------------------------------------------
__global__ void k_zero4(uint32_t* __restrict__ p) { p[threadIdx.x] = 0u; }

__global__ void k_conv_wqkv(const float* __restrict__ w, u16* __restrict__ o) {
  int idx = blockIdx.x * 256 + threadIdx.x;           // 768*2304
  if (idx >= 768 * 2304) return;
  int oc = idx / 2304, r = idx % 2304;
  int t = r >> 8, ic = r & 255;
  int kh = t / 3, kw = t % 3;
  o[idx] = f2bf(w[((oc * 256 + ic) * 3 + kh) * 3 + kw]);
}
__global__ void k_conv_wmod(const float* __restrict__ w, u16* __restrict__ o) {
  int idx = blockIdx.x * 256 + threadIdx.x;           // 512*768
  if (idx >= 512 * 768) return;
  int oc = idx / 768, r = idx % 768;
  int t = r >> 8, ic = r & 255;
  o[idx] = f2bf(w[(oc * 256 + ic) * 3 + t]);
}
__global__ void k_convert(const float* __restrict__ in, u16* __restrict__ o, int n) {
  int idx = blockIdx.x * 256 + threadIdx.x;
  if (idx < n) o[idx] = f2bf(in[idx]);
}

// ---------------------------------------------------------------------------
// x (B,256,4096) f32 -> ycatT[b][l][256+c] bf16 (x part of concat buffer)
// ---------------------------------------------------------------------------
__global__ __launch_bounds__(256) void k_xT(const float* __restrict__ x, u16* __restrict__ ycat) {
  __shared__ float tile[64 * 68];
  int b = blockIdx.z, c0 = blockIdx.y * 64, l0 = blockIdx.x * 64;
  int t = threadIdx.x;
  int cc = t >> 2, part = t & 3;
  const float* xp = x + ((int64_t)(b * 256 + c0 + cc)) * 4096 + l0 + part * 16;
#pragma unroll
  for (int j = 0; j < 4; ++j) {
    F4 v = *(const F4*)(xp + j * 4);
    float* tp = &tile[cc * 68 + part * 16 + j * 4];
    tp[0] = v.x; tp[1] = v.y; tp[2] = v.z; tp[3] = v.w;
  }
  __syncthreads();
  int l = t >> 2;
  u16* op = ycat + ((int64_t)b * 4096 + l0 + l) * 512 + 256 + c0 + part * 16;
  __align__(16) u16 tmp[16];
#pragma unroll
  for (int j = 0; j < 16; ++j) tmp[j] = f2bf(tile[(part * 16 + j) * 68 + l]);
  *(V16*)(op) = *(V16*)&tmp[0];
  *(V16*)(op + 8) = *(V16*)&tmp[8];
}

// ---------------------------------------------------------------------------
// m_q / m_k softmax, split over L (3 kernels)
// ---------------------------------------------------------------------------
__global__ __launch_bounds__(256) void k_mod_statsA(
    const u16* __restrict__ qkvT, const u16* __restrict__ modT,
    float2* __restrict__ part)
{
  int cg = blockIdx.x, ls = blockIdx.y;
  int b = blockIdx.z >> 1, sel = blockIdx.z & 1;
  int coff = cg * 32 + (sel ? 256 : 0);
  const u16* qp = qkvT + (int64_t)b * 4096 * 768 + coff;
  const u16* mp = modT + (int64_t)b * 4096 * 512 + coff;
  int t = threadIdx.x;
  int li = t >> 5, ci = t & 31;
  int l0 = ls * 512;
  float mmax = -3.4e38f, ssum = 0.f;
  for (int l = l0 + li; l < l0 + 512; l += 8) {
    float q = bf2f(qp[(int64_t)l * 768 + ci]);
    float m = bf2f(mp[(int64_t)l * 512 + ci]);
    float z = q * m; z = z > 0.f ? -z : 0.f;
    float nm = fmaxf(mmax, z);
    ssum = ssum * __expf(mmax - nm) + __expf(z - nm);
    mmax = nm;
  }
  __shared__ float sm[256], ssh[256];
  sm[t] = mmax; ssh[t] = ssum;
  __syncthreads();
  if (t < 32) {
    float M = sm[t], S = ssh[t];
#pragma unroll
    for (int k = 1; k < 8; ++k) {
      float m2 = sm[k * 32 + t], s2 = ssh[k * 32 + t];
      float nm = fmaxf(M, m2);
      S = S * __expf(M - nm) + s2 * __expf(m2 - nm);
      M = nm;
    }
    part[((int64_t)(b * 2 + sel) * 256 + cg * 32 + t) * 8 + ls] = make_float2(M, S);
  }
}

__global__ void k_mod_statsB(const float2* __restrict__ part, float2* __restrict__ fin) {
  int idx = blockIdx.x * 256 + threadIdx.x;   // 4096 channels
  float M = -3.4e38f, S = 0.f;
#pragma unroll
  for (int s = 0; s < 8; ++s) {
    float2 v = part[(int64_t)idx * 8 + s];
    float nm = fmaxf(M, v.x);
    S = S * __expf(M - nm) + v.y * __expf(v.x - nm);
    M = nm;
  }
  fin[idx] = make_float2(M, 1.0f / S);
}

__global__ __launch_bounds__(256) void k_mod_normC(
    const u16* __restrict__ qkvT, const u16* __restrict__ modT,
    const float2* __restrict__ fin, u16* __restrict__ mq, u16* __restrict__ mk)
{
  int cg = blockIdx.x, ls = blockIdx.y;
  int b = blockIdx.z >> 1, sel = blockIdx.z & 1;
  int coff = cg * 32 + (sel ? 256 : 0);
  const u16* qp = qkvT + (int64_t)b * 4096 * 768 + coff;
  const u16* mp = modT + (int64_t)b * 4096 * 512 + coff;
  u16* out = (sel ? mk : mq) + ((int64_t)b * 256 + cg * 32) * 4096;

  __shared__ float zt[64 * 33];
  int t = threadIdx.x;
  int lrow = t >> 2, part4 = t & 3;
  int co = t >> 3, lw = t & 7;
  float2 ms = fin[(int64_t)(b * 2 + sel) * 256 + cg * 32 + co];
  float Mv = ms.x, inv = ms.y;
  int lbase = ls * 512;
  for (int l0 = lbase; l0 < lbase + 512; l0 += 64) {
    V16 qv = *(const V16*)(qp + (int64_t)(l0 + lrow) * 768 + part4 * 8);
    V16 mv = *(const V16*)(mp + (int64_t)(l0 + lrow) * 512 + part4 * 8);
    const u16* qu = (const u16*)&qv;
    const u16* mu = (const u16*)&mv;
#pragma unroll
    for (int j = 0; j < 8; ++j) {
      float z = bf2f(qu[j]) * bf2f(mu[j]);
      zt[lrow * 33 + part4 * 8 + j] = z > 0.f ? -z : 0.f;
    }
    __syncthreads();
    __align__(16) u16 pk[8];
#pragma unroll
    for (int j = 0; j < 8; ++j) {
      float z = zt[(lw * 8 + j) * 33 + co];
      pk[j] = f2bf(__expf(z - Mv) * inv);
    }
    *(V16*)(out + (int64_t)co * 4096 + l0 + lw * 8) = *(V16*)&pk[0];
    __syncthreads();
  }
}

// softmax over d of (sum of split-K partials)*(1/16); block per (c,b)
__global__ __launch_bounds__(256) void k_softmax_attn(
    const float* __restrict__ sc, u16* __restrict__ ma, int nsplit, int64_t splitOff) {
  int c = blockIdx.x, b = blockIdx.y;
  int64_t base = ((int64_t)b * 256 + c) * 256;
  int t = threadIdx.x;
  float z = 0.f;
  for (int s = 0; s < nsplit; ++s) z += sc[(int64_t)s * splitOff + base + t];
  z *= 0.0625f;
  __shared__ float red[256];
  red[t] = z; __syncthreads();
  for (int s = 128; s > 0; s >>= 1) { if (t < s) red[t] = fmaxf(red[t], red[t + s]); __syncthreads(); }
  float M = red[0]; __syncthreads();
  float p = __expf(z - M);
  red[t] = p; __syncthreads();
  for (int s = 128; s > 0; s >>= 1) { if (t < s) red[t] += red[t + s]; __syncthreads(); }
  ma[base + t] = f2bf(p / red[0]);
}

// out = sigmoid(gpre)*res + (1-sigmoid(gpre))*y
__global__ __launch_bounds__(256) void k_final(const F4* __restrict__ gp, const F4* __restrict__ rs,
                                               const F4* __restrict__ yy, F4* __restrict__ o, int n4) {
  int i = blockIdx.x * 256 + threadIdx.x;
  int stride = gridDim.x * 256;
  for (; i < n4; i += stride) {
    F4 g = gp[i], r = rs[i], y = yy[i], ov;
    float gx = 1.f / (1.f + __expf(-g.x));
    float gy = 1.f / (1.f + __expf(-g.y));
    float gz = 1.f / (1.f + __expf(-g.z));
    float gw = 1.f / (1.f + __expf(-g.w));
    ov.x = gx * r.x + (1.f - gx) * y.x;
    ov.y = gy * r.y + (1.f - gy) * y.y;
    ov.z = gz * r.z + (1.f - gz) * y.z;
    ov.w = gw * r.w + (1.f - gw) * y.w;
    o[i] = ov;
  }
}

// ---------------------------------------------------------------------------
extern "C" void kernel_launch(void* const* d_in, const int* in_sizes, int n_in,
                              void* d_out, int out_size, void* d_ws, size_t ws_size,
                              hipStream_t stream) {
  (void)in_sizes; (void)n_in; (void)out_size; (void)ws_size;
  const float* x      = (const float*)d_in[0];
  const float* w_qkv  = (const float*)d_in[1];
  const float* w_mod  = (const float*)d_in[2];
  const float* w_res  = (const float*)d_in[3];
  const float* w_gate = (const float*)d_in[4];
  float* out = (float*)d_out;

  char* p = (char*)d_ws;
  auto take = [&](size_t n) { void* r = (void*)p; p += (n + 255) & ~(size_t)255; return r; };
  u16*    zpage  = (u16*)take(256);        // zero page for masked conv taps
  u16*    qkvT   = (u16*)take(50331648);   // [b][l][768] bf16 (q|k|v)
  u16*    modT   = (u16*)take(33554432);   // [b][l][512] bf16 (qm|km)
  u16*    ycatT  = (u16*)take(33554432);   // [b][l][512] bf16 (y|x)
  u16*    mq     = (u16*)take(16777216);   // [b][c][l] bf16
  u16*    mk     = (u16*)take(16777216);   // [b][d][l] bf16 (contiguous after mq)
  float*  scores = (float*)take(16777216); // [8 splits][b][c][d] f32
  u16*    mattn  = (u16*)take(1048576);    // [b][c][d] bf16
  float*  yb     = (float*)take(33554432); // [b][c][l] f32
  float2* partMS = (float2*)take(262144);  // [b*sel*c][8 lsplit] (M,S)
  float2* finMS  = (float2*)take(32768);   // [b*sel*c] (M, 1/S)
  u16*    Wa     = (u16*)take(3538944);    // 768 x 2304
  u16*    Wb     = (u16*)take(786432);     // 512 x 768
  u16*    Wg     = (u16*)take(262144);     // 256 x 512
  u16*    Wr     = (u16*)take(131072);     // 256 x 256
  float* gpre = (float*)modT;              // alias: modT dead after mod softmax
  float* resb = (float*)mq;                // alias: mq/mk dead after scores GEMM

  k_zero4<<<1, 64, 0, stream>>>((uint32_t*)zpage);
  k_conv_wqkv<<<6912, 256, 0, stream>>>(w_qkv, Wa);
  k_conv_wmod<<<1536, 256, 0, stream>>>(w_mod, Wb);
  k_convert<<<512, 256, 0, stream>>>(w_gate, Wg, 131072);
  k_convert<<<256, 256, 0, stream>>>(w_res, Wr, 65536);
  k_xT<<<dim3(64, 4, 8), 256, 0, stream>>>(x, ycatT);

  // qkv = conv2d(x, w_qkv): M=768 N=4096 K=9*256 -> qkvT bf16 (m201 geom)
  gemm201_bf16<2><<<384, 512, 0, stream>>>(
      Wa, ycatT + 256, qkvT,
      2304, 512, (int64_t)4096 * 512,
      768, (int64_t)4096 * 768, 3, zpage);

  // mod = conv1d(v, w_mod): M=512 N=4096 K=3*256 -> modT bf16 (m201 geom)
  gemm201_bf16<1><<<256, 512, 0, stream>>>(
      Wb, qkvT + 512, modT,
      768, 768, (int64_t)4096 * 768,
      512, (int64_t)4096 * 512, 2, zpage);

  // m_q/m_k softmax, L-split x8 for occupancy
  k_mod_statsA<<<dim3(8, 8, 16), 256, 0, stream>>>(qkvT, modT, partMS);
  k_mod_statsB<<<16, 256, 0, stream>>>(partMS, finMS);
  k_mod_normC<<<dim3(8, 8, 16), 256, 0, stream>>>(qkvT, modT, finMS, mq, mk);

  // scores[c][d] = sum_l mq[c,l]*mk[d,l]: M=256 N=256 K=4096, split-K x8
  gemm_bf16<0, true, false><<<dim3(2, 2, 64), 256, 0, stream>>>(
      mq, mk, scores, nullptr,
      512, 4096, (int64_t)256 * 4096,
      4096, (int64_t)256 * 4096,
      256, (int64_t)256 * 256,
      0, 0,
      8, 512, (int64_t)8 * 256 * 256, zpage);

  k_softmax_attn<<<dim3(256, 8), 256, 0, stream>>>(scores, mattn, 8, (int64_t)8 * 256 * 256);

  // y = m_attn @ v: M=256 N=4096 K=256 -> yb f32 + ycatT[:,0:256] bf16
  gemm_bf16<0, true, true><<<dim3(32, 2, 8), 256, 0, stream>>>(
      mattn, qkvT + 512, yb, ycatT,
      256, 256, (int64_t)256 * 256,
      768, (int64_t)4096 * 768,
      4096, (int64_t)256 * 4096,
      512, (int64_t)4096 * 512,
      1, 0, 0, zpage);

  // gpre = w_gate @ [y;x]: M=256 N=4096 K=512
  gemm_bf16<0, true, false><<<dim3(32, 2, 8), 256, 0, stream>>>(
      Wg, ycatT, gpre, nullptr,
      512, 512, 0,
      512, (int64_t)4096 * 512,
      4096, (int64_t)256 * 4096,
      0, 0,
      1, 0, 0, zpage);

  // res = w_res @ x: M=256 N=4096 K=256
  gemm_bf16<0, true, false><<<dim3(32, 2, 8), 256, 0, stream>>>(
      Wr, ycatT + 256, resb, nullptr,
      256, 256, 0,
      512, (int64_t)4096 * 512,
      4096, (int64_t)256 * 4096,
      0, 0,
      1, 0, 0, zpage);

  k_final<<<2048, 256, 0, stream>>>((const F4*)gpre, (const F4*)resb, (const F4*)yb, (F4*)out, 2097152);
}

// Round 8
// 347.380 us; speedup vs baseline: 1.0203x; 1.0203x over previous
//
#include <hip/hip_runtime.h>
#include <cstdint>

typedef unsigned short u16;
using bf16x8 = __attribute__((ext_vector_type(8))) short;   // 8 bf16 = 4 VGPR
using f32x4  = __attribute__((ext_vector_type(4))) float;   // MFMA acc

struct alignas(16) V16 { uint32_t a, b, c, d; };            // 16B chunk
struct alignas(8)  U16x4 { u16 a, b, c, d; };
struct alignas(16) F4 { float x, y, z, w; };

__device__ __forceinline__ u16 f2bf(float f) {              // RNE f32->bf16
  uint32_t u = __float_as_uint(f);
  u += 0x7fffu + ((u >> 16) & 1u);
  return (u16)(u >> 16);
}
__device__ __forceinline__ float bf2f(u16 h) {
  return __uint_as_float(((uint32_t)h) << 16);
}

// async global->LDS, 16B per lane; dest = wave-uniform base + lane*16 (linear)
#define GLOAD16(g, l) __builtin_amdgcn_global_load_lds(                         \
    (const __attribute__((address_space(1))) uint32_t*)(g),                     \
    (__attribute__((address_space(3))) uint32_t*)(l), 16, 0, 0)

// ===========================================================================
// 16-wave conv-GEMM: BM=256 BN=128, BK=64 slab, 1024 threads = 16 waves
// (4M x 4N, per-wave 64x32, acc[4][2]) -> 4 waves/SIMD for latency hiding.
//   Out[b][m][n] = sum_t sum_k A[m][t*256+k] * Bact[b][n+off(t)][k]
// LDS: ring-3 of (A 256x64 = 32KB + B 128x64 = 16KB) = 144 KiB.
// Rows 128B; swizzle chunk^=(row&7) (verified 0-conflict r4/r6), applied on
// global SOURCE + ds_read side; global_load_lds dest linear (rule #21).
// 2 phases/slab (K=32 each): {6 ds_read_b128 -> stage s+2 (A in P1, B in P2)
// -> barrier -> lgkmcnt(0)+sched_barrier -> setprio(1) 8 MFMA setprio(0) ->
// [boundary vmcnt(3)] -> barrier}. 3 loads/thread/slab -> counted vmcnt(3)
// at slab boundary only; vmcnt(0) only in tail (T3+T4+T5).
// Exact grids: conv2d 768 blocks = 3 rounds, conv1d 512 = 2 rounds.
// ===========================================================================
template<int MODE>
__global__ __launch_bounds__(1024, 1) void gemm16w_bf16(
    const u16* __restrict__ A, const u16* __restrict__ B, u16* __restrict__ otr,
    int sA, int sB, int64_t bBatch, int trStride, int64_t trBatch, int MT,
    const u16* __restrict__ zpage)
{
  constexpr int NS = (MODE == 2) ? 36 : 12;    // BK=64 slabs: NTAPS*(256/64)
  __shared__ __align__(16) u16 lds[73728];     // 144 KiB = 3 x (A16384+B8192)

  const int tid = threadIdx.x;
  // XCD-aware bijective swizzle (gridDim.x % 8 == 0)
  const int q = gridDim.x >> 3;
  const int flat = (blockIdx.x & 7) * q + (blockIdx.x >> 3);
  const int per_b = MT * 32;                   // 32 n-tiles of 128
  const int b = flat / per_b, rem = flat % per_b;
  const int ntile = rem / MT, mtile = rem % MT;
  const int m0 = mtile * 256, n0 = ntile * 128;
  const u16* Bb = B + (int64_t)b * bBatch;

  const int lane = tid & 63, wave = tid >> 6;
  const int wm = wave >> 2, wn = wave & 3;     // 4M x 4N waves, 64x32 each
  const int lr = lane & 15, lc = lane >> 4;

  // staging: thread -> (row srow (+128 for A j1), 16B chunk sch)
  const int srow = tid >> 3, sch = tid & 7;    // srow 0..127
  const int scs0 = sch ^ (srow & 7);
  const int scs1 = sch ^ ((srow + 128) & 7);   // == scs0 (128 ≡ 0 mod 8)
  const u16* aSrc0 = A + (int64_t)(m0 + srow) * sA + scs0 * 8;
  const u16* aSrc1 = A + (int64_t)(m0 + srow + 128) * sA + scs1 * 8;
  const u16* bSrc0 = Bb + (int64_t)(n0 + srow) * sB + scs0 * 8;
  const int bRow = n0 + srow;
  const int woff = wave * 512;                 // u16; per-wave LDS dest base

  auto stageA = [&](int s) {                   // 2 loads/thread
    const int kOff = (s >> 2) * 256 + ((s & 3) << 6);
    u16* dst = lds + (s % 3) * 24576;
    GLOAD16(aSrc0 + kOff, dst + woff);
    GLOAD16(aSrc1 + kOff, dst + 8192 + woff);
  };
  auto stageB = [&](int s) {                   // 1 load/thread
    const int tap = s >> 2, kc = (s & 3) << 6;
    int off, dh = 0, dw = 0;
    if constexpr (MODE == 2) { dh = tap / 3 - 1; dw = tap % 3 - 1; off = dh * 64 + dw; }
    else                     { off = tap - 1; }
    u16* dst = lds + (s % 3) * 24576 + 16384;
    bool ok;
    if constexpr (MODE == 2) {
      int hh = (bRow >> 6) + dh, ww = (bRow & 63) + dw;
      ok = ((unsigned)hh < 64u) && ((unsigned)ww < 64u);
    } else {
      ok = ((unsigned)(bRow + off) < 4096u);
    }
    const u16* src = ok ? (bSrc0 + (int64_t)off * sB + kc) : zpage;
    GLOAD16(src, dst + woff);
  };

  f32x4 acc[4][2];
#pragma unroll
  for (int i = 0; i < 4; ++i)
#pragma unroll
    for (int j = 0; j < 2; ++j) acc[i][j] = f32x4{0.f, 0.f, 0.f, 0.f};

  // prologue: stage slabs 0,1 (3 loads each); wait slab 0 -> vmcnt(3)
  stageA(0); stageB(0);
  stageA(1); stageB(1);
  asm volatile("s_waitcnt vmcnt(3)" ::: "memory");
  __builtin_amdgcn_s_barrier();
  __builtin_amdgcn_sched_barrier(0);

  for (int s = 0; s < NS; ++s) {
    const u16* As = lds + (s % 3) * 24576;
    const u16* Bs = As + 16384;
    const bool pf = (s + 2 < NS);

#pragma unroll
    for (int ks = 0; ks < 2; ++ks) {
      bf16x8 af[4], bf[2];
#pragma unroll
      for (int mf = 0; mf < 4; ++mf) {
        int row = wm * 64 + mf * 16 + lr;
        af[mf] = *(const bf16x8*)&As[row * 64 + (((ks * 4 + lc) ^ (row & 7)) * 8)];
      }
#pragma unroll
      for (int nf = 0; nf < 2; ++nf) {
        int row = wn * 32 + nf * 16 + lr;
        bf[nf] = *(const bf16x8*)&Bs[row * 64 + (((ks * 4 + lc) ^ (row & 7)) * 8)];
      }
      if (pf) { if (ks == 0) stageA(s + 2); else stageB(s + 2); }
      __builtin_amdgcn_s_barrier();
      asm volatile("s_waitcnt lgkmcnt(0)" ::: "memory");
      __builtin_amdgcn_sched_barrier(0);
      __builtin_amdgcn_s_setprio(1);
#pragma unroll
      for (int mf = 0; mf < 4; ++mf)
#pragma unroll
        for (int nf = 0; nf < 2; ++nf)
          acc[mf][nf] = __builtin_amdgcn_mfma_f32_16x16x32_bf16(af[mf], bf[nf], acc[mf][nf], 0, 0, 0);
      __builtin_amdgcn_s_setprio(0);
      if (ks == 1) {   // slab boundary: ensure slab s+1 landed for next iter
        if (pf)              { asm volatile("s_waitcnt vmcnt(3)" ::: "memory"); }
        else if (s + 1 < NS) { asm volatile("s_waitcnt vmcnt(0)" ::: "memory"); }
      }
      __builtin_amdgcn_s_barrier();
    }
  }

  // epilogue: C/D layout col=lane&15, row=(lane>>4)*4+reg; write transposed
#pragma unroll
  for (int mf = 0; mf < 4; ++mf)
#pragma unroll
    for (int nf = 0; nf < 2; ++nf) {
      f32x4 v = acc[mf][nf];
      int m = m0 + wm * 64 + mf * 16 + lc * 4;
      int n = n0 + wn * 32 + nf * 16 + lr;
      U16x4 pk{f2bf(v[0]), f2bf(v[1]), f2bf(v[2]), f2bf(v[3])};
      *(U16x4*)(otr + trBatch * b + (int64_t)n * trStride + m) = pk;
    }
}

// ---------------------------------------------------------------------------
// 128x128 GEMM (dense stages: scores, y, gate, res)
// ---------------------------------------------------------------------------
template<int MODE, bool WR_RM, bool WR_TR>
__global__ __launch_bounds__(256) void gemm_bf16(
    const u16* __restrict__ A, const u16* __restrict__ B,
    float* __restrict__ orm, u16* __restrict__ otr,
    int Kc, int sA, int64_t aBatch,
    int sB, int64_t bBatch,
    int rmStride, int64_t rmBatch,
    int trStride, int64_t trBatch,
    int nsplit, int kStep, int64_t splitOut,
    const u16* __restrict__ zpage)
{
  constexpr int NTAPS = (MODE == 2) ? 9 : (MODE == 1 ? 3 : 1);
  __shared__ __align__(16) u16 As[128 * 32];
  __shared__ __align__(16) u16 Bs[128 * 32];

  const int tid = threadIdx.x;
  int b = blockIdx.z, split = 0;
  if (nsplit > 1) { split = b % nsplit; b /= nsplit; }
  const int m0  = blockIdx.y * 128;
  const int n0  = blockIdx.x * 128;
  const int lane = tid & 63, wave = tid >> 6;
  const int wm = wave >> 1, wn = wave & 1;
  const int lr = lane & 15, lc = lane >> 4;

  f32x4 acc[4][4];
#pragma unroll
  for (int i = 0; i < 4; ++i)
#pragma unroll
    for (int j = 0; j < 4; ++j) acc[i][j] = f32x4{0.f, 0.f, 0.f, 0.f};

  const u16* Ab = A + (int64_t)b * aBatch + split * kStep;
  const u16* Bb = B + (int64_t)b * bBatch + split * kStep;

  const int srow = tid >> 2;
  const int sc   = tid & 3;
  const int scs  = sc ^ (srow & 3);

  for (int t = 0; t < NTAPS; ++t) {
    int dh = 0, dw = 0, off = 0;
    if constexpr (MODE == 2) { dh = t / 3 - 1; dw = t % 3 - 1; off = dh * 64 + dw; }
    if constexpr (MODE == 1) { off = t - 1; }

    for (int kc = 0; kc < Kc; kc += 32) {
      const int kA = t * Kc + kc;
#pragma unroll
      for (int it = 0; it < 2; ++it) {
        int row = srow + it * 64;
        GLOAD16(Ab + (int64_t)(m0 + row) * sA + kA + scs * 8,
                &As[wave * 512 + it * 2048]);
      }
#pragma unroll
      for (int it = 0; it < 2; ++it) {
        int row = srow + it * 64;
        int l = n0 + row;
        int gl = l + off;
        bool ok = true;
        if constexpr (MODE == 2) {
          int hh = (l >> 6) + dh, ww = (l & 63) + dw;
          ok = ((unsigned)hh < 64u) && ((unsigned)ww < 64u);
        }
        if constexpr (MODE == 1) { ok = ((unsigned)gl < 4096u); }
        const u16* src = ok ? (Bb + (int64_t)gl * sB + kc + scs * 8) : zpage;
        GLOAD16(src, &Bs[wave * 512 + it * 2048]);
      }
      __syncthreads();

      bf16x8 af[4], bfr[4];
#pragma unroll
      for (int mf = 0; mf < 4; ++mf) {
        int row = wm * 64 + mf * 16 + lr;
        int cs = lc ^ (row & 3);
        af[mf] = *(const bf16x8*)&As[row * 32 + cs * 8];
      }
#pragma unroll
      for (int nf = 0; nf < 4; ++nf) {
        int row = wn * 64 + nf * 16 + lr;
        int cs = lc ^ (row & 3);
        bfr[nf] = *(const bf16x8*)&Bs[row * 32 + cs * 8];
      }
#pragma unroll
      for (int mf = 0; mf < 4; ++mf)
#pragma unroll
        for (int nf = 0; nf < 4; ++nf)
          acc[mf][nf] = __builtin_amdgcn_mfma_f32_16x16x32_bf16(af[mf], bfr[nf], acc[mf][nf], 0, 0, 0);
      __syncthreads();
    }
  }

#pragma unroll
  for (int mf = 0; mf < 4; ++mf) {
#pragma unroll
    for (int nf = 0; nf < 4; ++nf) {
      f32x4 v = acc[mf][nf];
      int m = m0 + wm * 64 + mf * 16 + lc * 4;
      int n = n0 + wn * 64 + nf * 16 + lr;
      if constexpr (WR_RM) {
        float* p = orm + splitOut * split + rmBatch * b + (int64_t)m * rmStride + n;
#pragma unroll
        for (int r = 0; r < 4; ++r) p[(int64_t)r * rmStride] = v[r];
      }
      if constexpr (WR_TR) {
        U16x4 pk{f2bf(v[0]), f2bf(v[1]), f2bf(v[2]), f2bf(v[3])};
        *(U16x4*)(otr + trBatch * b + (int64_t)n * trStride + m) = pk;
      }
    }
  }
}

// ---------------------------------------------------------------------------
// weight converts + zero page
// ---------------------------------------------------------------------------
__global__ void k_zero4(uint32_t* __restrict__ p) { p[threadIdx.x] = 0u; }

__global__ void k_conv_wqkv(const float* __restrict__ w, u16* __restrict__ o) {
  int idx = blockIdx.x * 256 + threadIdx.x;           // 768*2304
  if (idx >= 768 * 2304) return;
  int oc = idx / 2304, r = idx % 2304;
  int t = r >> 8, ic = r & 255;
  int kh = t / 3, kw = t % 3;
  o[idx] = f2bf(w[((oc * 256 + ic) * 3 + kh) * 3 + kw]);
}
__global__ void k_conv_wmod(const float* __restrict__ w, u16* __restrict__ o) {
  int idx = blockIdx.x * 256 + threadIdx.x;           // 512*768
  if (idx >= 512 * 768) return;
  int oc = idx / 768, r = idx % 768;
  int t = r >> 8, ic = r & 255;
  o[idx] = f2bf(w[(oc * 256 + ic) * 3 + t]);
}
__global__ void k_convert(const float* __restrict__ in, u16* __restrict__ o, int n) {
  int idx = blockIdx.x * 256 + threadIdx.x;
  if (idx < n) o[idx] = f2bf(in[idx]);
}

// ---------------------------------------------------------------------------
// x (B,256,4096) f32 -> ycatT[b][l][256+c] bf16 (x part of concat buffer)
// ---------------------------------------------------------------------------
__global__ __launch_bounds__(256) void k_xT(const float* __restrict__ x, u16* __restrict__ ycat) {
  __shared__ float tile[64 * 68];
  int b = blockIdx.z, c0 = blockIdx.y * 64, l0 = blockIdx.x * 64;
  int t = threadIdx.x;
  int cc = t >> 2, part = t & 3;
  const float* xp = x + ((int64_t)(b * 256 + c0 + cc)) * 4096 + l0 + part * 16;
#pragma unroll
  for (int j = 0; j < 4; ++j) {
    F4 v = *(const F4*)(xp + j * 4);
    float* tp = &tile[cc * 68 + part * 16 + j * 4];
    tp[0] = v.x; tp[1] = v.y; tp[2] = v.z; tp[3] = v.w;
  }
  __syncthreads();
  int l = t >> 2;
  u16* op = ycat + ((int64_t)b * 4096 + l0 + l) * 512 + 256 + c0 + part * 16;
  __align__(16) u16 tmp[16];
#pragma unroll
  for (int j = 0; j < 16; ++j) tmp[j] = f2bf(tile[(part * 16 + j) * 68 + l]);
  *(V16*)(op) = *(V16*)&tmp[0];
  *(V16*)(op + 8) = *(V16*)&tmp[8];
}

// ---------------------------------------------------------------------------
// m_q / m_k softmax, split over L (3 kernels)
// ---------------------------------------------------------------------------
__global__ __launch_bounds__(256) void k_mod_statsA(
    const u16* __restrict__ qkvT, const u16* __restrict__ modT,
    float2* __restrict__ part)
{
  int cg = blockIdx.x, ls = blockIdx.y;
  int b = blockIdx.z >> 1, sel = blockIdx.z & 1;
  int coff = cg * 32 + (sel ? 256 : 0);
  const u16* qp = qkvT + (int64_t)b * 4096 * 768 + coff;
  const u16* mp = modT + (int64_t)b * 4096 * 512 + coff;
  int t = threadIdx.x;
  int li = t >> 5, ci = t & 31;
  int l0 = ls * 512;
  float mmax = -3.4e38f, ssum = 0.f;
  for (int l = l0 + li; l < l0 + 512; l += 8) {
    float q = bf2f(qp[(int64_t)l * 768 + ci]);
    float m = bf2f(mp[(int64_t)l * 512 + ci]);
    float z = q * m; z = z > 0.f ? -z : 0.f;
    float nm = fmaxf(mmax, z);
    ssum = ssum * __expf(mmax - nm) + __expf(z - nm);
    mmax = nm;
  }
  __shared__ float sm[256], ssh[256];
  sm[t] = mmax; ssh[t] = ssum;
  __syncthreads();
  if (t < 32) {
    float M = sm[t], S = ssh[t];
#pragma unroll
    for (int k = 1; k < 8; ++k) {
      float m2 = sm[k * 32 + t], s2 = ssh[k * 32 + t];
      float nm = fmaxf(M, m2);
      S = S * __expf(M - nm) + s2 * __expf(m2 - nm);
      M = nm;
    }
    part[((int64_t)(b * 2 + sel) * 256 + cg * 32 + t) * 8 + ls] = make_float2(M, S);
  }
}

__global__ void k_mod_statsB(const float2* __restrict__ part, float2* __restrict__ fin) {
  int idx = blockIdx.x * 256 + threadIdx.x;   // 4096 channels
  float M = -3.4e38f, S = 0.f;
#pragma unroll
  for (int s = 0; s < 8; ++s) {
    float2 v = part[(int64_t)idx * 8 + s];
    float nm = fmaxf(M, v.x);
    S = S * __expf(M - nm) + v.y * __expf(v.x - nm);
    M = nm;
  }
  fin[idx] = make_float2(M, 1.0f / S);
}

__global__ __launch_bounds__(256) void k_mod_normC(
    const u16* __restrict__ qkvT, const u16* __restrict__ modT,
    const float2* __restrict__ fin, u16* __restrict__ mq, u16* __restrict__ mk)
{
  int cg = blockIdx.x, ls = blockIdx.y;
  int b = blockIdx.z >> 1, sel = blockIdx.z & 1;
  int coff = cg * 32 + (sel ? 256 : 0);
  const u16* qp = qkvT + (int64_t)b * 4096 * 768 + coff;
  const u16* mp = modT + (int64_t)b * 4096 * 512 + coff;
  u16* out = (sel ? mk : mq) + ((int64_t)b * 256 + cg * 32) * 4096;

  __shared__ float zt[64 * 33];
  int t = threadIdx.x;
  int lrow = t >> 2, part4 = t & 3;
  int co = t >> 3, lw = t & 7;
  float2 ms = fin[(int64_t)(b * 2 + sel) * 256 + cg * 32 + co];
  float Mv = ms.x, inv = ms.y;
  int lbase = ls * 512;
  for (int l0 = lbase; l0 < lbase + 512; l0 += 64) {
    V16 qv = *(const V16*)(qp + (int64_t)(l0 + lrow) * 768 + part4 * 8);
    V16 mv = *(const V16*)(mp + (int64_t)(l0 + lrow) * 512 + part4 * 8);
    const u16* qu = (const u16*)&qv;
    const u16* mu = (const u16*)&mv;
#pragma unroll
    for (int j = 0; j < 8; ++j) {
      float z = bf2f(qu[j]) * bf2f(mu[j]);
      zt[lrow * 33 + part4 * 8 + j] = z > 0.f ? -z : 0.f;
    }
    __syncthreads();
    __align__(16) u16 pk[8];
#pragma unroll
    for (int j = 0; j < 8; ++j) {
      float z = zt[(lw * 8 + j) * 33 + co];
      pk[j] = f2bf(__expf(z - Mv) * inv);
    }
    *(V16*)(out + (int64_t)co * 4096 + l0 + lw * 8) = *(V16*)&pk[0];
    __syncthreads();
  }
}

// softmax over d of (sum of split-K partials)*(1/16); block per (c,b)
__global__ __launch_bounds__(256) void k_softmax_attn(
    const float* __restrict__ sc, u16* __restrict__ ma, int nsplit, int64_t splitOff) {
  int c = blockIdx.x, b = blockIdx.y;
  int64_t base = ((int64_t)b * 256 + c) * 256;
  int t = threadIdx.x;
  float z = 0.f;
  for (int s = 0; s < nsplit; ++s) z += sc[(int64_t)s * splitOff + base + t];
  z *= 0.0625f;
  __shared__ float red[256];
  red[t] = z; __syncthreads();
  for (int s = 128; s > 0; s >>= 1) { if (t < s) red[t] = fmaxf(red[t], red[t + s]); __syncthreads(); }
  float M = red[0]; __syncthreads();
  float p = __expf(z - M);
  red[t] = p; __syncthreads();
  for (int s = 128; s > 0; s >>= 1) { if (t < s) red[t] += red[t + s]; __syncthreads(); }
  ma[base + t] = f2bf(p / red[0]);
}

// out = sigmoid(gpre)*res + (1-sigmoid(gpre))*y
__global__ __launch_bounds__(256) void k_final(const F4* __restrict__ gp, const F4* __restrict__ rs,
                                               const F4* __restrict__ yy, F4* __restrict__ o, int n4) {
  int i = blockIdx.x * 256 + threadIdx.x;
  int stride = gridDim.x * 256;
  for (; i < n4; i += stride) {
    F4 g = gp[i], r = rs[i], y = yy[i], ov;
    float gx = 1.f / (1.f + __expf(-g.x));
    float gy = 1.f / (1.f + __expf(-g.y));
    float gz = 1.f / (1.f + __expf(-g.z));
    float gw = 1.f / (1.f + __expf(-g.w));
    ov.x = gx * r.x + (1.f - gx) * y.x;
    ov.y = gy * r.y + (1.f - gy) * y.y;
    ov.z = gz * r.z + (1.f - gz) * y.z;
    ov.w = gw * r.w + (1.f - gw) * y.w;
    o[i] = ov;
  }
}

// ---------------------------------------------------------------------------
extern "C" void kernel_launch(void* const* d_in, const int* in_sizes, int n_in,
                              void* d_out, int out_size, void* d_ws, size_t ws_size,
                              hipStream_t stream) {
  (void)in_sizes; (void)n_in; (void)out_size; (void)ws_size;
  const float* x      = (const float*)d_in[0];
  const float* w_qkv  = (const float*)d_in[1];
  const float* w_mod  = (const float*)d_in[2];
  const float* w_res  = (const float*)d_in[3];
  const float* w_gate = (const float*)d_in[4];
  float* out = (float*)d_out;

  char* p = (char*)d_ws;
  auto take = [&](size_t n) { void* r = (void*)p; p += (n + 255) & ~(size_t)255; return r; };
  u16*    zpage  = (u16*)take(256);        // zero page for masked conv taps
  u16*    qkvT   = (u16*)take(50331648);   // [b][l][768] bf16 (q|k|v)
  u16*    modT   = (u16*)take(33554432);   // [b][l][512] bf16 (qm|km)
  u16*    ycatT  = (u16*)take(33554432);   // [b][l][512] bf16 (y|x)
  u16*    mq     = (u16*)take(16777216);   // [b][c][l] bf16
  u16*    mk     = (u16*)take(16777216);   // [b][d][l] bf16 (contiguous after mq)
  float*  scores = (float*)take(16777216); // [8 splits][b][c][d] f32
  u16*    mattn  = (u16*)take(1048576);    // [b][c][d] bf16
  float*  yb     = (float*)take(33554432); // [b][c][l] f32
  float2* partMS = (float2*)take(262144);  // [b*sel*c][8 lsplit] (M,S)
  float2* finMS  = (float2*)take(32768);   // [b*sel*c] (M, 1/S)
  u16*    Wa     = (u16*)take(3538944);    // 768 x 2304
  u16*    Wb     = (u16*)take(786432);     // 512 x 768
  u16*    Wg     = (u16*)take(262144);     // 256 x 512
  u16*    Wr     = (u16*)take(131072);     // 256 x 256
  float* gpre = (float*)modT;              // alias: modT dead after mod softmax
  float* resb = (float*)mq;                // alias: mq/mk dead after scores GEMM

  k_zero4<<<1, 64, 0, stream>>>((uint32_t*)zpage);
  k_conv_wqkv<<<6912, 256, 0, stream>>>(w_qkv, Wa);
  k_conv_wmod<<<1536, 256, 0, stream>>>(w_mod, Wb);
  k_convert<<<512, 256, 0, stream>>>(w_gate, Wg, 131072);
  k_convert<<<256, 256, 0, stream>>>(w_res, Wr, 65536);
  k_xT<<<dim3(64, 4, 8), 256, 0, stream>>>(x, ycatT);

  // qkv = conv2d(x, w_qkv): M=768 N=4096 K=9*256 -> qkvT bf16 (16-wave)
  gemm16w_bf16<2><<<768, 1024, 0, stream>>>(
      Wa, ycatT + 256, qkvT,
      2304, 512, (int64_t)4096 * 512,
      768, (int64_t)4096 * 768, 3, zpage);

  // mod = conv1d(v, w_mod): M=512 N=4096 K=3*256 -> modT bf16 (16-wave)
  gemm16w_bf16<1><<<512, 1024, 0, stream>>>(
      Wb, qkvT + 512, modT,
      768, 768, (int64_t)4096 * 768,
      512, (int64_t)4096 * 512, 2, zpage);

  // m_q/m_k softmax, L-split x8 for occupancy
  k_mod_statsA<<<dim3(8, 8, 16), 256, 0, stream>>>(qkvT, modT, partMS);
  k_mod_statsB<<<16, 256, 0, stream>>>(partMS, finMS);
  k_mod_normC<<<dim3(8, 8, 16), 256, 0, stream>>>(qkvT, modT, finMS, mq, mk);

  // scores[c][d] = sum_l mq[c,l]*mk[d,l]: M=256 N=256 K=4096, split-K x8
  gemm_bf16<0, true, false><<<dim3(2, 2, 64), 256, 0, stream>>>(
      mq, mk, scores, nullptr,
      512, 4096, (int64_t)256 * 4096,
      4096, (int64_t)256 * 4096,
      256, (int64_t)256 * 256,
      0, 0,
      8, 512, (int64_t)8 * 256 * 256, zpage);

  k_softmax_attn<<<dim3(256, 8), 256, 0, stream>>>(scores, mattn, 8, (int64_t)8 * 256 * 256);

  // y = m_attn @ v: M=256 N=4096 K=256 -> yb f32 + ycatT[:,0:256] bf16
  gemm_bf16<0, true, true><<<dim3(32, 2, 8), 256, 0, stream>>>(
      mattn, qkvT + 512, yb, ycatT,
      256, 256, (int64_t)256 * 256,
      768, (int64_t)4096 * 768,
      4096, (int64_t)256 * 4096,
      512, (int64_t)4096 * 512,
      1, 0, 0, zpage);

  // gpre = w_gate @ [y;x]: M=256 N=4096 K=512
  gemm_bf16<0, true, false><<<dim3(32, 2, 8), 256, 0, stream>>>(
      Wg, ycatT, gpre, nullptr,
      512, 512, 0,
      512, (int64_t)4096 * 512,
      4096, (int64_t)256 * 4096,
      0, 0,
      1, 0, 0, zpage);

  // res = w_res @ x: M=256 N=4096 K=256
  gemm_bf16<0, true, false><<<dim3(32, 2, 8), 256, 0, stream>>>(
      Wr, ycatT + 256, resb, nullptr,
      256, 256, 0,
      512, (int64_t)4096 * 512,
      4096, (int64_t)256 * 4096,
      0, 0,
      1, 0, 0, zpage);

  k_final<<<2048, 256, 0, stream>>>((const F4*)gpre, (const F4*)resb, (const F4*)yb, (F4*)out, 2097152);
}

// Round 9
// 337.963 us; speedup vs baseline: 1.0487x; 1.0279x over previous
//
#include <hip/hip_runtime.h>
#include <cstdint>

typedef unsigned short u16;
using bf16x8 = __attribute__((ext_vector_type(8))) short;   // 8 bf16 = 4 VGPR
using f32x4  = __attribute__((ext_vector_type(4))) float;   // MFMA acc

struct alignas(16) V16 { uint32_t a, b, c, d; };            // 16B chunk
struct alignas(8)  U16x4 { u16 a, b, c, d; };
struct alignas(16) F4 { float x, y, z, w; };

__device__ __forceinline__ u16 f2bf(float f) {              // RNE f32->bf16
  uint32_t u = __float_as_uint(f);
  u += 0x7fffu + ((u >> 16) & 1u);
  return (u16)(u >> 16);
}
__device__ __forceinline__ float bf2f(u16 h) {
  return __uint_as_float(((uint32_t)h) << 16);
}

// async global->LDS, 16B per lane; dest = wave-uniform base + lane*16 (linear)
#define GLOAD16(g, l) __builtin_amdgcn_global_load_lds(                         \
    (const __attribute__((address_space(1))) uint32_t*)(g),                     \
    (__attribute__((address_space(3))) uint32_t*)(l), 16, 0, 0)

// ===========================================================================
// Overlap-pipelined conv-GEMM: BM=BN=256, BK=64 slab, 8 waves (2M x 4N),
// per-wave 128x64 (acc[8][4]).
//   Out[b][m][n] = sum_t sum_k A[m][t*256+k] * Bact[b][n+off(t)][k]
// KEY CHANGE vs r4-r8: NO intra-slab barriers / lgkmcnt(0) / sched fences.
// All prior variants serialized {LDS-read burst} then {MFMA burst} via
// lockstep fences -> util == MFMA/(MFMA+LDS) ~= 29-45% (matches r4-r8 PMC).
// Here the compiler tracks ds_read->MFMA deps and emits counted lgkmcnt,
// overlapping LDS drain with MFMA issue (m97/m201 mechanism). Overlapped
// ceiling at this intensity: LDS 384cy vs MFMA 310cy per K=32 -> ~81%.
// LDS ring-2 dbuf, 128 KiB. Single-barrier protocol per slab:
//   iter s reads buf s&1; stages slab s+1 into buf (s+1)&1 (holds s-1,
//   consumed before the prior boundary barrier since every ds_read result
//   is consumed by MFMA pre-barrier); boundary = vmcnt(0)+s_barrier+
//   sched_barrier(0). Loads get the whole ~700cy compute phase to land (L2).
// Swizzle: 128-B rows, chunk ^= (row&7) (verified 0-conflict r4/r6/r8),
// applied on global SOURCE + ds_read side; gload_lds dest linear (rule #21).
// ===========================================================================
template<int MODE>
__global__ __launch_bounds__(512, 2) void gemmOv_bf16(
    const u16* __restrict__ A, const u16* __restrict__ B, u16* __restrict__ otr,
    int sA, int sB, int64_t bBatch, int trStride, int64_t trBatch, int MT,
    const u16* __restrict__ zpage)
{
  constexpr int NS = (MODE == 2) ? 36 : 12;    // BK=64 slabs: NTAPS*(256/64)
  __shared__ __align__(16) u16 lds[65536];     // 128 KiB = 2 x (A32KB+B32KB)

  const int tid = threadIdx.x;
  // XCD-aware bijective swizzle (gridDim.x % 8 == 0)
  const int q = gridDim.x >> 3;
  const int flat = (blockIdx.x & 7) * q + (blockIdx.x >> 3);
  const int per_b = MT * 16;                   // 16 n-tiles of 256
  const int b = flat / per_b, rem = flat % per_b;
  const int ntile = rem / MT, mtile = rem % MT;
  const int m0 = mtile * 256, n0 = ntile * 256;
  const u16* Bb = B + (int64_t)b * bBatch;

  const int lane = tid & 63, wave = tid >> 6;
  const int wm = wave >> 2, wn = wave & 3;     // 2M x 4N waves, 128x64 each
  const int lr = lane & 15, lc = lane >> 4;

  // staging: load (wave w, j) fills 8 rows w*32+j*8.. (+7), contiguous 1KB.
  // lane l -> row_local l>>3, chunk l&7; source chunk pre-swizzled.
  const int srow = wave * 32 + (lane >> 3);    // base row (j adds 8)
  const int sch  = lane & 7;
  const int scs  = sch ^ (srow & 7);           // (srow+8j)&7 == srow&7
  const u16* aSrc[4];
  const u16* bSrc[4];
  int bRow[4];
#pragma unroll
  for (int j = 0; j < 4; ++j) {
    aSrc[j] = A + (int64_t)(m0 + srow + j * 8) * sA + scs * 8;
    bSrc[j] = Bb + (int64_t)(n0 + srow + j * 8) * sB + scs * 8;
    bRow[j] = n0 + srow + j * 8;
  }
  const int wdst = wave * 2048;                // u16; + j*512 per load

  auto stageA = [&](int s) {                   // 4 loads/thread
    const int kOff = (s >> 2) * 256 + ((s & 3) << 6);
    u16* dst = lds + (s & 1) * 32768 + wdst;
#pragma unroll
    for (int j = 0; j < 4; ++j)
      GLOAD16(aSrc[j] + kOff, dst + j * 512);
  };
  auto stageB = [&](int s) {                   // 4 loads/thread (tap-masked)
    const int tap = s >> 2, kc = (s & 3) << 6;
    int off, dh = 0, dw = 0;
    if constexpr (MODE == 2) { dh = tap / 3 - 1; dw = tap % 3 - 1; off = dh * 64 + dw; }
    else                     { off = tap - 1; }
    u16* dst = lds + (s & 1) * 32768 + 16384 + wdst;
#pragma unroll
    for (int j = 0; j < 4; ++j) {
      bool ok;
      if constexpr (MODE == 2) {
        int hh = (bRow[j] >> 6) + dh, ww = (bRow[j] & 63) + dw;
        ok = ((unsigned)hh < 64u) && ((unsigned)ww < 64u);
      } else {
        ok = ((unsigned)(bRow[j] + off) < 4096u);
      }
      const u16* src = ok ? (bSrc[j] + (int64_t)off * sB + kc) : zpage;
      GLOAD16(src, dst + j * 512);
    }
  };

  f32x4 acc[8][4];
#pragma unroll
  for (int i = 0; i < 8; ++i)
#pragma unroll
    for (int j = 0; j < 4; ++j) acc[i][j] = f32x4{0.f, 0.f, 0.f, 0.f};

  // prologue: stage slab 0, drain, barrier
  stageA(0); stageB(0);
  asm volatile("s_waitcnt vmcnt(0)" ::: "memory");
  __builtin_amdgcn_s_barrier();
  __builtin_amdgcn_sched_barrier(0);

  for (int s = 0; s < NS; ++s) {
    const u16* As = lds + (s & 1) * 32768;
    const u16* Bs = As + 16384;
    const bool pf = (s + 1 < NS);
    bf16x8 bfr[4], af[4], af2[4];

    // ---- k-half 0: reads + stage A(s+1) + 32 MFMA (compiler-interleaved)
#pragma unroll
    for (int nf = 0; nf < 4; ++nf) {
      int row = wn * 64 + nf * 16 + lr;
      bfr[nf] = *(const bf16x8*)&Bs[row * 64 + ((lc ^ (row & 7)) * 8)];
    }
#pragma unroll
    for (int mf = 0; mf < 4; ++mf) {
      int row = wm * 128 + mf * 16 + lr;
      af[mf] = *(const bf16x8*)&As[row * 64 + ((lc ^ (row & 7)) * 8)];
    }
    if (pf) stageA(s + 1);
#pragma unroll
    for (int mf = 0; mf < 4; ++mf) {
      int row = wm * 128 + 64 + mf * 16 + lr;
      af2[mf] = *(const bf16x8*)&As[row * 64 + ((lc ^ (row & 7)) * 8)];
    }
#pragma unroll
    for (int mf = 0; mf < 4; ++mf)
#pragma unroll
      for (int nf = 0; nf < 4; ++nf)
        acc[mf][nf] = __builtin_amdgcn_mfma_f32_16x16x32_bf16(af[mf], bfr[nf], acc[mf][nf], 0, 0, 0);
#pragma unroll
    for (int mf = 0; mf < 4; ++mf)
#pragma unroll
      for (int nf = 0; nf < 4; ++nf)
        acc[4 + mf][nf] = __builtin_amdgcn_mfma_f32_16x16x32_bf16(af2[mf], bfr[nf], acc[4 + mf][nf], 0, 0, 0);

    // ---- k-half 1: reads + stage B(s+1) + 32 MFMA
#pragma unroll
    for (int nf = 0; nf < 4; ++nf) {
      int row = wn * 64 + nf * 16 + lr;
      bfr[nf] = *(const bf16x8*)&Bs[row * 64 + (((4 + lc) ^ (row & 7)) * 8)];
    }
#pragma unroll
    for (int mf = 0; mf < 4; ++mf) {
      int row = wm * 128 + mf * 16 + lr;
      af[mf] = *(const bf16x8*)&As[row * 64 + (((4 + lc) ^ (row & 7)) * 8)];
    }
    if (pf) stageB(s + 1);
#pragma unroll
    for (int mf = 0; mf < 4; ++mf) {
      int row = wm * 128 + 64 + mf * 16 + lr;
      af2[mf] = *(const bf16x8*)&As[row * 64 + (((4 + lc) ^ (row & 7)) * 8)];
    }
#pragma unroll
    for (int mf = 0; mf < 4; ++mf)
#pragma unroll
      for (int nf = 0; nf < 4; ++nf)
        acc[mf][nf] = __builtin_amdgcn_mfma_f32_16x16x32_bf16(af[mf], bfr[nf], acc[mf][nf], 0, 0, 0);
#pragma unroll
    for (int mf = 0; mf < 4; ++mf)
#pragma unroll
      for (int nf = 0; nf < 4; ++nf)
        acc[4 + mf][nf] = __builtin_amdgcn_mfma_f32_16x16x32_bf16(af2[mf], bfr[nf], acc[4 + mf][nf], 0, 0, 0);

    // ---- slab boundary: next-slab loads landed, all waves done reading
    if (pf) {
      asm volatile("s_waitcnt vmcnt(0)" ::: "memory");
      __builtin_amdgcn_s_barrier();
      __builtin_amdgcn_sched_barrier(0);
    }
  }

  // epilogue: C/D layout col=lane&15, row=(lane>>4)*4+reg; write transposed
#pragma unroll
  for (int mf = 0; mf < 8; ++mf)
#pragma unroll
    for (int nf = 0; nf < 4; ++nf) {
      f32x4 v = acc[mf][nf];
      int m = m0 + wm * 128 + mf * 16 + lc * 4;
      int n = n0 + wn * 64 + nf * 16 + lr;
      U16x4 pk{f2bf(v[0]), f2bf(v[1]), f2bf(v[2]), f2bf(v[3])};
      *(U16x4*)(otr + trBatch * b + (int64_t)n * trStride + m) = pk;
    }
}

// ---------------------------------------------------------------------------
// 128x128 GEMM (dense stages: scores, y, gate, res)
// ---------------------------------------------------------------------------
template<int MODE, bool WR_RM, bool WR_TR>
__global__ __launch_bounds__(256) void gemm_bf16(
    const u16* __restrict__ A, const u16* __restrict__ B,
    float* __restrict__ orm, u16* __restrict__ otr,
    int Kc, int sA, int64_t aBatch,
    int sB, int64_t bBatch,
    int rmStride, int64_t rmBatch,
    int trStride, int64_t trBatch,
    int nsplit, int kStep, int64_t splitOut,
    const u16* __restrict__ zpage)
{
  constexpr int NTAPS = (MODE == 2) ? 9 : (MODE == 1 ? 3 : 1);
  __shared__ __align__(16) u16 As[128 * 32];
  __shared__ __align__(16) u16 Bs[128 * 32];

  const int tid = threadIdx.x;
  int b = blockIdx.z, split = 0;
  if (nsplit > 1) { split = b % nsplit; b /= nsplit; }
  const int m0  = blockIdx.y * 128;
  const int n0  = blockIdx.x * 128;
  const int lane = tid & 63, wave = tid >> 6;
  const int wm = wave >> 1, wn = wave & 1;
  const int lr = lane & 15, lc = lane >> 4;

  f32x4 acc[4][4];
#pragma unroll
  for (int i = 0; i < 4; ++i)
#pragma unroll
    for (int j = 0; j < 4; ++j) acc[i][j] = f32x4{0.f, 0.f, 0.f, 0.f};

  const u16* Ab = A + (int64_t)b * aBatch + split * kStep;
  const u16* Bb = B + (int64_t)b * bBatch + split * kStep;

  const int srow = tid >> 2;
  const int sc   = tid & 3;
  const int scs  = sc ^ (srow & 3);

  for (int t = 0; t < NTAPS; ++t) {
    int dh = 0, dw = 0, off = 0;
    if constexpr (MODE == 2) { dh = t / 3 - 1; dw = t % 3 - 1; off = dh * 64 + dw; }
    if constexpr (MODE == 1) { off = t - 1; }

    for (int kc = 0; kc < Kc; kc += 32) {
      const int kA = t * Kc + kc;
#pragma unroll
      for (int it = 0; it < 2; ++it) {
        int row = srow + it * 64;
        GLOAD16(Ab + (int64_t)(m0 + row) * sA + kA + scs * 8,
                &As[wave * 512 + it * 2048]);
      }
#pragma unroll
      for (int it = 0; it < 2; ++it) {
        int row = srow + it * 64;
        int l = n0 + row;
        int gl = l + off;
        bool ok = true;
        if constexpr (MODE == 2) {
          int hh = (l >> 6) + dh, ww = (l & 63) + dw;
          ok = ((unsigned)hh < 64u) && ((unsigned)ww < 64u);
        }
        if constexpr (MODE == 1) { ok = ((unsigned)gl < 4096u); }
        const u16* src = ok ? (Bb + (int64_t)gl * sB + kc + scs * 8) : zpage;
        GLOAD16(src, &Bs[wave * 512 + it * 2048]);
      }
      __syncthreads();

      bf16x8 af[4], bfr[4];
#pragma unroll
      for (int mf = 0; mf < 4; ++mf) {
        int row = wm * 64 + mf * 16 + lr;
        int cs = lc ^ (row & 3);
        af[mf] = *(const bf16x8*)&As[row * 32 + cs * 8];
      }
#pragma unroll
      for (int nf = 0; nf < 4; ++nf) {
        int row = wn * 64 + nf * 16 + lr;
        int cs = lc ^ (row & 3);
        bfr[nf] = *(const bf16x8*)&Bs[row * 32 + cs * 8];
      }
#pragma unroll
      for (int mf = 0; mf < 4; ++mf)
#pragma unroll
        for (int nf = 0; nf < 4; ++nf)
          acc[mf][nf] = __builtin_amdgcn_mfma_f32_16x16x32_bf16(af[mf], bfr[nf], acc[mf][nf], 0, 0, 0);
      __syncthreads();
    }
  }

#pragma unroll
  for (int mf = 0; mf < 4; ++mf) {
#pragma unroll
    for (int nf = 0; nf < 4; ++nf) {
      f32x4 v = acc[mf][nf];
      int m = m0 + wm * 64 + mf * 16 + lc * 4;
      int n = n0 + wn * 64 + nf * 16 + lr;
      if constexpr (WR_RM) {
        float* p = orm + splitOut * split + rmBatch * b + (int64_t)m * rmStride + n;
#pragma unroll
        for (int r = 0; r < 4; ++r) p[(int64_t)r * rmStride] = v[r];
      }
      if constexpr (WR_TR) {
        U16x4 pk{f2bf(v[0]), f2bf(v[1]), f2bf(v[2]), f2bf(v[3])};
        *(U16x4*)(otr + trBatch * b + (int64_t)n * trStride + m) = pk;
      }
    }
  }
}

// ---------------------------------------------------------------------------
// weight converts + zero page
// ---------------------------------------------------------------------------
__global__ void k_zero4(uint32_t* __restrict__ p) { p[threadIdx.x] = 0u; }

__global__ void k_conv_wqkv(const float* __restrict__ w, u16* __restrict__ o) {
  int idx = blockIdx.x * 256 + threadIdx.x;           // 768*2304
  if (idx >= 768 * 2304) return;
  int oc = idx / 2304, r = idx % 2304;
  int t = r >> 8, ic = r & 255;
  int kh = t / 3, kw = t % 3;
  o[idx] = f2bf(w[((oc * 256 + ic) * 3 + kh) * 3 + kw]);
}
__global__ void k_conv_wmod(const float* __restrict__ w, u16* __restrict__ o) {
  int idx = blockIdx.x * 256 + threadIdx.x;           // 512*768
  if (idx >= 512 * 768) return;
  int oc = idx / 768, r = idx % 768;
  int t = r >> 8, ic = r & 255;
  o[idx] = f2bf(w[(oc * 256 + ic) * 3 + t]);
}
__global__ void k_convert(const float* __restrict__ in, u16* __restrict__ o, int n) {
  int idx = blockIdx.x * 256 + threadIdx.x;
  if (idx < n) o[idx] = f2bf(in[idx]);
}

// ---------------------------------------------------------------------------
// x (B,256,4096) f32 -> ycatT[b][l][256+c] bf16 (x part of concat buffer)
// ---------------------------------------------------------------------------
__global__ __launch_bounds__(256) void k_xT(const float* __restrict__ x, u16* __restrict__ ycat) {
  __shared__ float tile[64 * 68];
  int b = blockIdx.z, c0 = blockIdx.y * 64, l0 = blockIdx.x * 64;
  int t = threadIdx.x;
  int cc = t >> 2, part = t & 3;
  const float* xp = x + ((int64_t)(b * 256 + c0 + cc)) * 4096 + l0 + part * 16;
#pragma unroll
  for (int j = 0; j < 4; ++j) {
    F4 v = *(const F4*)(xp + j * 4);
    float* tp = &tile[cc * 68 + part * 16 + j * 4];
    tp[0] = v.x; tp[1] = v.y; tp[2] = v.z; tp[3] = v.w;
  }
  __syncthreads();
  int l = t >> 2;
  u16* op = ycat + ((int64_t)b * 4096 + l0 + l) * 512 + 256 + c0 + part * 16;
  __align__(16) u16 tmp[16];
#pragma unroll
  for (int j = 0; j < 16; ++j) tmp[j] = f2bf(tile[(part * 16 + j) * 68 + l]);
  *(V16*)(op) = *(V16*)&tmp[0];
  *(V16*)(op + 8) = *(V16*)&tmp[8];
}

// ---------------------------------------------------------------------------
// m_q / m_k softmax, split over L (3 kernels)
// ---------------------------------------------------------------------------
__global__ __launch_bounds__(256) void k_mod_statsA(
    const u16* __restrict__ qkvT, const u16* __restrict__ modT,
    float2* __restrict__ part)
{
  int cg = blockIdx.x, ls = blockIdx.y;
  int b = blockIdx.z >> 1, sel = blockIdx.z & 1;
  int coff = cg * 32 + (sel ? 256 : 0);
  const u16* qp = qkvT + (int64_t)b * 4096 * 768 + coff;
  const u16* mp = modT + (int64_t)b * 4096 * 512 + coff;
  int t = threadIdx.x;
  int li = t >> 5, ci = t & 31;
  int l0 = ls * 512;
  float mmax = -3.4e38f, ssum = 0.f;
  for (int l = l0 + li; l < l0 + 512; l += 8) {
    float q = bf2f(qp[(int64_t)l * 768 + ci]);
    float m = bf2f(mp[(int64_t)l * 512 + ci]);
    float z = q * m; z = z > 0.f ? -z : 0.f;
    float nm = fmaxf(mmax, z);
    ssum = ssum * __expf(mmax - nm) + __expf(z - nm);
    mmax = nm;
  }
  __shared__ float sm[256], ssh[256];
  sm[t] = mmax; ssh[t] = ssum;
  __syncthreads();
  if (t < 32) {
    float M = sm[t], S = ssh[t];
#pragma unroll
    for (int k = 1; k < 8; ++k) {
      float m2 = sm[k * 32 + t], s2 = ssh[k * 32 + t];
      float nm = fmaxf(M, m2);
      S = S * __expf(M - nm) + s2 * __expf(m2 - nm);
      M = nm;
    }
    part[((int64_t)(b * 2 + sel) * 256 + cg * 32 + t) * 8 + ls] = make_float2(M, S);
  }
}

__global__ void k_mod_statsB(const float2* __restrict__ part, float2* __restrict__ fin) {
  int idx = blockIdx.x * 256 + threadIdx.x;   // 4096 channels
  float M = -3.4e38f, S = 0.f;
#pragma unroll
  for (int s = 0; s < 8; ++s) {
    float2 v = part[(int64_t)idx * 8 + s];
    float nm = fmaxf(M, v.x);
    S = S * __expf(M - nm) + v.y * __expf(v.x - nm);
    M = nm;
  }
  fin[idx] = make_float2(M, 1.0f / S);
}

__global__ __launch_bounds__(256) void k_mod_normC(
    const u16* __restrict__ qkvT, const u16* __restrict__ modT,
    const float2* __restrict__ fin, u16* __restrict__ mq, u16* __restrict__ mk)
{
  int cg = blockIdx.x, ls = blockIdx.y;
  int b = blockIdx.z >> 1, sel = blockIdx.z & 1;
  int coff = cg * 32 + (sel ? 256 : 0);
  const u16* qp = qkvT + (int64_t)b * 4096 * 768 + coff;
  const u16* mp = modT + (int64_t)b * 4096 * 512 + coff;
  u16* out = (sel ? mk : mq) + ((int64_t)b * 256 + cg * 32) * 4096;

  __shared__ float zt[64 * 33];
  int t = threadIdx.x;
  int lrow = t >> 2, part4 = t & 3;
  int co = t >> 3, lw = t & 7;
  float2 ms = fin[(int64_t)(b * 2 + sel) * 256 + cg * 32 + co];
  float Mv = ms.x, inv = ms.y;
  int lbase = ls * 512;
  for (int l0 = lbase; l0 < lbase + 512; l0 += 64) {
    V16 qv = *(const V16*)(qp + (int64_t)(l0 + lrow) * 768 + part4 * 8);
    V16 mv = *(const V16*)(mp + (int64_t)(l0 + lrow) * 512 + part4 * 8);
    const u16* qu = (const u16*)&qv;
    const u16* mu = (const u16*)&mv;
#pragma unroll
    for (int j = 0; j < 8; ++j) {
      float z = bf2f(qu[j]) * bf2f(mu[j]);
      zt[lrow * 33 + part4 * 8 + j] = z > 0.f ? -z : 0.f;
    }
    __syncthreads();
    __align__(16) u16 pk[8];
#pragma unroll
    for (int j = 0; j < 8; ++j) {
      float z = zt[(lw * 8 + j) * 33 + co];
      pk[j] = f2bf(__expf(z - Mv) * inv);
    }
    *(V16*)(out + (int64_t)co * 4096 + l0 + lw * 8) = *(V16*)&pk[0];
    __syncthreads();
  }
}

// softmax over d of (sum of split-K partials)*(1/16); block per (c,b)
__global__ __launch_bounds__(256) void k_softmax_attn(
    const float* __restrict__ sc, u16* __restrict__ ma, int nsplit, int64_t splitOff) {
  int c = blockIdx.x, b = blockIdx.y;
  int64_t base = ((int64_t)b * 256 + c) * 256;
  int t = threadIdx.x;
  float z = 0.f;
  for (int s = 0; s < nsplit; ++s) z += sc[(int64_t)s * splitOff + base + t];
  z *= 0.0625f;
  __shared__ float red[256];
  red[t] = z; __syncthreads();
  for (int s = 128; s > 0; s >>= 1) { if (t < s) red[t] = fmaxf(red[t], red[t + s]); __syncthreads(); }
  float M = red[0]; __syncthreads();
  float p = __expf(z - M);
  red[t] = p; __syncthreads();
  for (int s = 128; s > 0; s >>= 1) { if (t < s) red[t] += red[t + s]; __syncthreads(); }
  ma[base + t] = f2bf(p / red[0]);
}

// out = sigmoid(gpre)*res + (1-sigmoid(gpre))*y
__global__ __launch_bounds__(256) void k_final(const F4* __restrict__ gp, const F4* __restrict__ rs,
                                               const F4* __restrict__ yy, F4* __restrict__ o, int n4) {
  int i = blockIdx.x * 256 + threadIdx.x;
  int stride = gridDim.x * 256;
  for (; i < n4; i += stride) {
    F4 g = gp[i], r = rs[i], y = yy[i], ov;
    float gx = 1.f / (1.f + __expf(-g.x));
    float gy = 1.f / (1.f + __expf(-g.y));
    float gz = 1.f / (1.f + __expf(-g.z));
    float gw = 1.f / (1.f + __expf(-g.w));
    ov.x = gx * r.x + (1.f - gx) * y.x;
    ov.y = gy * r.y + (1.f - gy) * y.y;
    ov.z = gz * r.z + (1.f - gz) * y.z;
    ov.w = gw * r.w + (1.f - gw) * y.w;
    o[i] = ov;
  }
}

// ---------------------------------------------------------------------------
extern "C" void kernel_launch(void* const* d_in, const int* in_sizes, int n_in,
                              void* d_out, int out_size, void* d_ws, size_t ws_size,
                              hipStream_t stream) {
  (void)in_sizes; (void)n_in; (void)out_size; (void)ws_size;
  const float* x      = (const float*)d_in[0];
  const float* w_qkv  = (const float*)d_in[1];
  const float* w_mod  = (const float*)d_in[2];
  const float* w_res  = (const float*)d_in[3];
  const float* w_gate = (const float*)d_in[4];
  float* out = (float*)d_out;

  char* p = (char*)d_ws;
  auto take = [&](size_t n) { void* r = (void*)p; p += (n + 255) & ~(size_t)255; return r; };
  u16*    zpage  = (u16*)take(256);        // zero page for masked conv taps
  u16*    qkvT   = (u16*)take(50331648);   // [b][l][768] bf16 (q|k|v)
  u16*    modT   = (u16*)take(33554432);   // [b][l][512] bf16 (qm|km)
  u16*    ycatT  = (u16*)take(33554432);   // [b][l][512] bf16 (y|x)
  u16*    mq     = (u16*)take(16777216);   // [b][c][l] bf16
  u16*    mk     = (u16*)take(16777216);   // [b][d][l] bf16 (contiguous after mq)
  float*  scores = (float*)take(16777216); // [8 splits][b][c][d] f32
  u16*    mattn  = (u16*)take(1048576);    // [b][c][d] bf16
  float*  yb     = (float*)take(33554432); // [b][c][l] f32
  float2* partMS = (float2*)take(262144);  // [b*sel*c][8 lsplit] (M,S)
  float2* finMS  = (float2*)take(32768);   // [b*sel*c] (M, 1/S)
  u16*    Wa     = (u16*)take(3538944);    // 768 x 2304
  u16*    Wb     = (u16*)take(786432);     // 512 x 768
  u16*    Wg     = (u16*)take(262144);     // 256 x 512
  u16*    Wr     = (u16*)take(131072);     // 256 x 256
  float* gpre = (float*)modT;              // alias: modT dead after mod softmax
  float* resb = (float*)mq;                // alias: mq/mk dead after scores GEMM

  k_zero4<<<1, 64, 0, stream>>>((uint32_t*)zpage);
  k_conv_wqkv<<<6912, 256, 0, stream>>>(w_qkv, Wa);
  k_conv_wmod<<<1536, 256, 0, stream>>>(w_mod, Wb);
  k_convert<<<512, 256, 0, stream>>>(w_gate, Wg, 131072);
  k_convert<<<256, 256, 0, stream>>>(w_res, Wr, 65536);
  k_xT<<<dim3(64, 4, 8), 256, 0, stream>>>(x, ycatT);

  // qkv = conv2d(x, w_qkv): M=768 N=4096 K=9*256 -> qkvT bf16 (overlap-pipe)
  gemmOv_bf16<2><<<384, 512, 0, stream>>>(
      Wa, ycatT + 256, qkvT,
      2304, 512, (int64_t)4096 * 512,
      768, (int64_t)4096 * 768, 3, zpage);

  // mod = conv1d(v, w_mod): M=512 N=4096 K=3*256 -> modT bf16 (overlap-pipe)
  gemmOv_bf16<1><<<256, 512, 0, stream>>>(
      Wb, qkvT + 512, modT,
      768, 768, (int64_t)4096 * 768,
      512, (int64_t)4096 * 512, 2, zpage);

  // m_q/m_k softmax, L-split x8 for occupancy
  k_mod_statsA<<<dim3(8, 8, 16), 256, 0, stream>>>(qkvT, modT, partMS);
  k_mod_statsB<<<16, 256, 0, stream>>>(partMS, finMS);
  k_mod_normC<<<dim3(8, 8, 16), 256, 0, stream>>>(qkvT, modT, finMS, mq, mk);

  // scores[c][d] = sum_l mq[c,l]*mk[d,l]: M=256 N=256 K=4096, split-K x8
  gemm_bf16<0, true, false><<<dim3(2, 2, 64), 256, 0, stream>>>(
      mq, mk, scores, nullptr,
      512, 4096, (int64_t)256 * 4096,
      4096, (int64_t)256 * 4096,
      256, (int64_t)256 * 256,
      0, 0,
      8, 512, (int64_t)8 * 256 * 256, zpage);

  k_softmax_attn<<<dim3(256, 8), 256, 0, stream>>>(scores, mattn, 8, (int64_t)8 * 256 * 256);

  // y = m_attn @ v: M=256 N=4096 K=256 -> yb f32 + ycatT[:,0:256] bf16
  gemm_bf16<0, true, true><<<dim3(32, 2, 8), 256, 0, stream>>>(
      mattn, qkvT + 512, yb, ycatT,
      256, 256, (int64_t)256 * 256,
      768, (int64_t)4096 * 768,
      4096, (int64_t)256 * 4096,
      512, (int64_t)4096 * 512,
      1, 0, 0, zpage);

  // gpre = w_gate @ [y;x]: M=256 N=4096 K=512
  gemm_bf16<0, true, false><<<dim3(32, 2, 8), 256, 0, stream>>>(
      Wg, ycatT, gpre, nullptr,
      512, 512, 0,
      512, (int64_t)4096 * 512,
      4096, (int64_t)256 * 4096,
      0, 0,
      1, 0, 0, zpage);

  // res = w_res @ x: M=256 N=4096 K=256
  gemm_bf16<0, true, false><<<dim3(32, 2, 8), 256, 0, stream>>>(
      Wr, ycatT + 256, resb, nullptr,
      256, 256, 0,
      512, (int64_t)4096 * 512,
      4096, (int64_t)256 * 4096,
      0, 0,
      1, 0, 0, zpage);

  k_final<<<2048, 256, 0, stream>>>((const F4*)gpre, (const F4*)resb, (const F4*)yb, (F4*)out, 2097152);
}